// Round 11
// baseline (200.231 us; speedup 1.0000x reference)
//
#include <hip/hip_runtime.h>
#include <hip/hip_bf16.h>

#define CFEAT 128
#define NODES 2048
#define NM    219            // 9 deg1 + 45 deg2 + 165 deg3 monomials
#define NSTEP 7              // K padded to 224 = 7*32 (16x16x32 MFMA)
#define P_REPS 24            // instrumentation: surface p1/p2 in rocprof top-5

typedef __attribute__((ext_vector_type(8))) short short8;
typedef __attribute__((ext_vector_type(4))) float f32x4;
typedef __attribute__((ext_vector_type(4))) unsigned int uint4v;

// ---- ws float offsets: [0, 917504B) = Wf bf16 fragments, then: ------------
#define OFF3 262144                          // U3s [9][165][16]
#define OFF2 (OFF3 + 9*165*16)               // U2s [9][45][4]
#define OFF1 (OFF2 + 9*45*4)                 // U1s [9][9]

__device__ __forceinline__ short f2bf(float x) {
    union { __hip_bfloat16 b; short s; } cv;
    cv.b = __float2bfloat16(x);
    return cv.s;
}

// ---- monomial index -> (deg,i,j,l), i<=j<=l (constexpr) --------------------
struct MIdx { int deg, i, j, l; };
__host__ __device__ constexpr MIdx decode_c(int idx) {
    if (idx < 9) return {1, idx, 0, 0};
    int t = idx - 9;
    for (int i = 0; i < 9; ++i)
        for (int j = i; j < 9; ++j) {
            int cnt = 10 - j;
            if (t < cnt) {
                if (t == 0) return {2, i, j, 0};
                return {3, i, j, j + t - 1};
            }
            t -= cnt;
        }
    return {0, 0, 0, 0};
}
__host__ __device__ constexpr int h2c(int n) { return n * (n + 1) / 2; }
__host__ __device__ constexpr int g3c(int n) { return n * (n + 1) * (n + 2) / 6; }
__host__ __device__ constexpr int tri3c(int i, int j, int l) {
    return (165 - g3c(9 - i)) + (h2c(9 - i) - h2c(9 - j)) + (l - j);
}
__host__ __device__ constexpr int pair2c(int i, int j) {
    return (45 - h2c(9 - i)) + (j - i);
}

struct MTbl { int v[224]; };
__host__ __device__ constexpr MTbl gen_tbl() {
    MTbl t{};
    for (int k = 0; k < 224; ++k) {
        if (k < NM) {
            MIdx d = decode_c(k);
            int sub = (d.deg == 1) ? d.i : (d.deg == 2) ? pair2c(d.i, d.j)
                                                        : tri3c(d.i, d.j, d.l);
            t.v[k] = d.deg | (sub << 4);
        } else t.v[k] = 0;
    }
    return t;
}
__device__ constexpr MTbl MONO_TBL = gen_tbl();

template<int K>
__device__ __forceinline__ float mono_val_t(const float a[9]) {
    if constexpr (K >= NM) return 0.f;
    else {
        constexpr MIdx d = decode_c(K);
        if constexpr (d.deg == 1) return a[d.i];
        else if constexpr (d.deg == 2) return a[d.i] * a[d.j];
        else return a[d.i] * a[d.j] * a[d.l];
    }
}

// pack two monomials to 2xbf16 in one dword (validated r4-r10)
template<int KB, int E2>
__device__ __forceinline__ unsigned pack2(const float a[9]) {
    const float lo = mono_val_t<KB + 2 * E2>(a);
    const float hi = mono_val_t<KB + 2 * E2 + 1>(a);
    return __builtin_amdgcn_perm(__float_as_uint(hi) + 0x8000u,
                                 __float_as_uint(lo) + 0x8000u, 0x07060302u);
}
template<int KB>
__device__ __forceinline__ uint4v build_granule(const float a[9]) {
    return uint4v{pack2<KB,0>(a), pack2<KB,1>(a), pack2<KB,2>(a), pack2<KB,3>(a)};
}

// ---- P1 body: channel-independent symmetrization (r6 verbatim) -------------
__device__ void p1_body(int mg, int y, int t,
    const float* __restrict__ Us1, const float* __restrict__ Us2, const float* __restrict__ Us3,
    const float* __restrict__ Up1, const float* __restrict__ Up2, const float* __restrict__ Up3,
    const float* __restrict__ Ud1, const float* __restrict__ Ud2, const float* __restrict__ Ud3,
    float* __restrict__ ws_f)
{
    const float *U1, *U2, *U3; int K2, K3, ml;
    if (mg == 0)     { U1 = Us1; U2 = Us2; U3 = Us3; K2 = 2; K3 = 5;  ml = 0; }
    else if (mg < 4) { U1 = Up1; U2 = Up2; U3 = Up3; K2 = 3; K3 = 8;  ml = mg - 1; }
    else             { U1 = Ud1; U2 = Ud2; U3 = Ud3; K2 = 4; K3 = 10; ml = mg - 4; }

    if (y < 11) {
        if (t >= 240) return;
        const int tri = y * 15 + (t >> 4);
        const int k   = t & 15;
        if (k >= K3) return;
        int i = 0, j = 0, l = 0, r = tri;
        bool done = false;
        for (i = 0; i < 9 && !done; ++i)
            for (j = i; j < 9; ++j) {
                int cnt = 9 - j;
                if (r < cnt) { l = j + r; done = true; break; }
                r -= cnt;
            }
        --i;
        const int e0=(i*9+j)*9+l, e1=(i*9+l)*9+j, e2=(j*9+i)*9+l,
                  e3=(j*9+l)*9+i, e4=(l*9+i)*9+j, e5=(l*9+j)*9+i;
        const float* B3 = U3 + (size_t)ml * 729 * K3 + k;
        float v = B3[(size_t)e0 * K3];
        if (e1 != e0)                                     v += B3[(size_t)e1 * K3];
        if (e2 != e0 && e2 != e1)                         v += B3[(size_t)e2 * K3];
        if (e3 != e0 && e3 != e1 && e3 != e2)             v += B3[(size_t)e3 * K3];
        if (e4 != e0 && e4 != e1 && e4 != e2 && e4 != e3) v += B3[(size_t)e4 * K3];
        if (e5 != e0 && e5 != e1 && e5 != e2 && e5 != e3 && e5 != e4)
                                                          v += B3[(size_t)e5 * K3];
        ws_f[OFF3 + (mg * 165 + tri) * 16 + k] = v;
    } else {
        if (t < 180) {
            int pr = t >> 2, k = t & 3;
            if (k >= K2) return;
            int i = 0, j = 0, r = pr;
            for (i = 0; i < 9; ++i) {
                int cnt = 9 - i;
                if (r < cnt) { j = i + r; break; }
                r -= cnt;
            }
            float v = U2[((size_t)(ml * 9 + i) * 9 + j) * K2 + k];
            if (i != j) v += U2[((size_t)(ml * 9 + j) * 9 + i) * K2 + k];
            ws_f[OFF2 + (mg * 45 + pr) * 4 + k] = v;
        } else if (t < 189) {
            const int i = t - 180;
            ws_f[OFF1 + mg * 9 + i] = U1[ml * 9 + i];
        }
    }
}

__global__ __launch_bounds__(256) void symcon_p1(
    const float* __restrict__ Us1, const float* __restrict__ Us2, const float* __restrict__ Us3,
    const float* __restrict__ Up1, const float* __restrict__ Up2, const float* __restrict__ Up3,
    const float* __restrict__ Ud1, const float* __restrict__ Ud2, const float* __restrict__ Ud3,
    float* __restrict__ ws_f)
{
    #pragma unroll 1
    for (int rep = 0; rep < P_REPS; ++rep) {   // instrumentation: x24, idempotent
        p1_body(blockIdx.x, blockIdx.y, threadIdx.x,
                Us1, Us2, Us3, Up1, Up2, Up3, Ud1, Ud2, Ud3, ws_f);
        asm volatile("" ::: "memory");         // keep reps live (rule #17)
    }
}

// ---- P2 body: per-channel weighting into bf16 B-fragment layout (r10) ------
__device__ __forceinline__ void p2_body(
    const float* __restrict__ ws_f,
    const float* __restrict__ ws1, const float* __restrict__ ws2, const float* __restrict__ ws3,
    const float* __restrict__ wp1, const float* __restrict__ wp2, const float* __restrict__ wp3,
    const float* __restrict__ wd1, const float* __restrict__ wd2, const float* __restrict__ wd3,
    short* __restrict__ Wf)
{
    const int c = blockIdx.x, s = blockIdx.y >> 1;
    const int slot = ((blockIdx.y & 1) << 8) | threadIdx.x;
    const int lane = slot >> 3, e = slot & 7;
    const int k = s * 32 + ((lane >> 4) * 8) + e;
    const int m = lane & 15;
    float v = 0.f;
    if (k < NM && m < 9) {
        const int pk  = MONO_TBL.v[k];
        const int deg = pk & 15, sub = pk >> 4;
        const float *w1, *w2, *w3; int K2, K3;
        if (m == 0)     { w1 = ws1; w2 = ws2; w3 = ws3; K2 = 2; K3 = 5;  }
        else if (m < 4) { w1 = wp1; w2 = wp2; w3 = wp3; K2 = 3; K3 = 8;  }
        else            { w1 = wd1; w2 = wd2; w3 = wd3; K2 = 4; K3 = 10; }
        if (deg == 1) {
            v = ws_f[OFF1 + m * 9 + sub] * w1[c];
        } else if (deg == 2) {
            const float* u = ws_f + OFF2 + (m * 45 + sub) * 4;
            for (int kk = 0; kk < K2; ++kk) v = fmaf(u[kk], w2[kk * CFEAT + c], v);
        } else {
            const float* u = ws_f + OFF3 + (m * 165 + sub) * 16;
            for (int kk = 0; kk < K3; ++kk) v = fmaf(u[kk], w3[kk * CFEAT + c], v);
        }
    }
    Wf[(((size_t)c * NSTEP + s) * 64 + lane) * 8 + e] = f2bf(v);
}

__global__ __launch_bounds__(256) void symcon_p2(
    const float* __restrict__ ws_f,
    const float* __restrict__ ws1, const float* __restrict__ ws2, const float* __restrict__ ws3,
    const float* __restrict__ wp1, const float* __restrict__ wp2, const float* __restrict__ wp3,
    const float* __restrict__ wd1, const float* __restrict__ wd2, const float* __restrict__ wd3,
    short* __restrict__ Wf)
{
    #pragma unroll 1
    for (int rep = 0; rep < P_REPS; ++rep) {   // instrumentation: x24, idempotent
        p2_body(ws_f, ws1, ws2, ws3, wp1, wp2, wp3, wd1, wd2, wd3, Wf);
        asm volatile("" ::: "memory");         // keep reps live (rule #17)
    }
}

// ---- hot step (r6 verbatim) ------------------------------------------------
template<int S>
__device__ __forceinline__ void do_step(const float a[9], char* wrbase, const char* rdbase,
                                        const short8 bfrag[NSTEP], f32x4 acc[4])
{
    const uint4v g0 = build_granule<S * 32 +  0>(a);
    const uint4v g1 = build_granule<S * 32 +  8>(a);
    const uint4v g2 = build_granule<S * 32 + 16>(a);
    const uint4v g3 = build_granule<S * 32 + 24>(a);
    *(uint4v*)(wrbase       ) = g0;
    *(uint4v*)(wrbase + 1024) = g1;
    *(uint4v*)(wrbase + 2048) = g2;
    *(uint4v*)(wrbase + 3072) = g3;
    #pragma unroll
    for (int t = 0; t < 4; ++t) {
        short8 af = *(const short8*)(rdbase + t * 256);
        acc[t] = __builtin_amdgcn_mfma_f32_16x16x32_bf16(af, bfrag[S], acc[t], 0, 0, 0);
    }
}

// ---- hot: r10 verbatim (float4-vectorized staging) -------------------------
__global__ __launch_bounds__(256, 4) void symcon_hot(
    const float* __restrict__ A, const short* __restrict__ Wf, float* __restrict__ out)
{
    const int tid = threadIdx.x;
    const int w = tid >> 6, l = tid & 63;
    const int p = l & 15, q = l >> 4;
    const int c0 = blockIdx.x * 4;
    const int nb = blockIdx.y * 64;

    __shared__ float sA[64 * 37];                     // 9472 B staging (pad 37)
    __shared__ __align__(16) char phiAll[4 * 4096];   // 16 KB wave-private phi

    const size_t gbase = (size_t)nb * (CFEAT * 9) + (size_t)c0 * 9;

    #pragma unroll
    for (int e = tid; e < 576; e += 256) {
        const int n = e / 9, f = e - n * 9;
        const float4 v = *(const float4*)(A + gbase + (size_t)n * (CFEAT * 9) + f * 4);
        const int base = n * 37 + f * 4;
        sA[base] = v.x; sA[base + 1] = v.y; sA[base + 2] = v.z; sA[base + 3] = v.w;
    }

    const short8* Wc = (const short8*)Wf + (size_t)(c0 + w) * NSTEP * 64;
    short8 bfrag[NSTEP];
    #pragma unroll
    for (int s = 0; s < NSTEP; ++s) bfrag[s] = Wc[s * 64 + l];

    __syncthreads();

    float a[9];
    #pragma unroll
    for (int x = 0; x < 9; ++x) a[x] = sA[l * 37 + w * 9 + x];

    char* const phiW   = phiAll + w * 4096;
    char* const wrbase = phiW + l * 16;
    const char* const rdbase = phiW + q * 1024 + p * 16;

    f32x4 acc[4];
    #pragma unroll
    for (int t = 0; t < 4; ++t) acc[t] = f32x4{0.f, 0.f, 0.f, 0.f};

    do_step<0>(a, wrbase, rdbase, bfrag, acc);
    do_step<1>(a, wrbase, rdbase, bfrag, acc);
    do_step<2>(a, wrbase, rdbase, bfrag, acc);
    do_step<3>(a, wrbase, rdbase, bfrag, acc);
    do_step<4>(a, wrbase, rdbase, bfrag, acc);
    do_step<5>(a, wrbase, rdbase, bfrag, acc);
    do_step<6>(a, wrbase, rdbase, bfrag, acc);

    __syncthreads();
    if (p < 9) {
        #pragma unroll
        for (int t = 0; t < 4; ++t)
            #pragma unroll
            for (int r = 0; r < 4; ++r)
                sA[(t * 16 + q * 4 + r) * 37 + w * 9 + p] = acc[t][r];
    }
    __syncthreads();

    #pragma unroll
    for (int e = tid; e < 576; e += 256) {
        const int n = e / 9, f = e - n * 9;
        const int base = n * 37 + f * 4;
        const float4 v{sA[base], sA[base + 1], sA[base + 2], sA[base + 3]};
        *(float4*)(out + gbase + (size_t)n * (CFEAT * 9) + f * 4) = v;
    }
}

extern "C" void kernel_launch(void* const* d_in, const int* in_sizes, int n_in,
                              void* d_out, int out_size, void* d_ws, size_t ws_size,
                              hipStream_t stream)
{
    const float* A   = (const float*)d_in[0];
    const float* Us1 = (const float*)d_in[1];  const float* ws1 = (const float*)d_in[2];
    const float* Us2 = (const float*)d_in[3];  const float* ws2 = (const float*)d_in[4];
    const float* Us3 = (const float*)d_in[5];  const float* ws3 = (const float*)d_in[6];
    const float* Up1 = (const float*)d_in[7];  const float* wp1 = (const float*)d_in[8];
    const float* Up2 = (const float*)d_in[9];  const float* wp2 = (const float*)d_in[10];
    const float* Up3 = (const float*)d_in[11]; const float* wp3 = (const float*)d_in[12];
    const float* Ud1 = (const float*)d_in[13]; const float* wd1 = (const float*)d_in[14];
    const float* Ud2 = (const float*)d_in[15]; const float* wd2 = (const float*)d_in[16];
    const float* Ud3 = (const float*)d_in[17]; const float* wd3 = (const float*)d_in[18];
    float* out  = (float*)d_out;
    float* ws_f = (float*)d_ws;
    short* Wf   = (short*)d_ws;

    symcon_p1<<<dim3(9, 12), 256, 0, stream>>>(
        Us1, Us2, Us3, Up1, Up2, Up3, Ud1, Ud2, Ud3, ws_f);

    symcon_p2<<<dim3(CFEAT, NSTEP * 2), 256, 0, stream>>>(
        ws_f, ws1, ws2, ws3, wp1, wp2, wp3, wd1, wd2, wd3, Wf);

    symcon_hot<<<dim3(CFEAT / 4, NODES / 64), 256, 0, stream>>>(A, Wf, out);
}

// Round 12
// 48.941 us; speedup vs baseline: 4.0913x; 4.0913x over previous
//
#include <hip/hip_runtime.h>
#include <hip/hip_bf16.h>

#define CFEAT 128
#define NODES 2048
#define NM    219            // 9 deg1 + 45 deg2 + 165 deg3 monomials
#define NSTEP 7              // K padded to 224 = 7*32 (16x16x32 MFMA)
#define CL    8              // channels per prep block

typedef __attribute__((ext_vector_type(8))) short short8;
typedef __attribute__((ext_vector_type(4))) float f32x4;
typedef __attribute__((ext_vector_type(4))) unsigned int uint4v;

__device__ __forceinline__ short f2bf(float x) {
    union { __hip_bfloat16 b; short s; } cv;
    cv.b = __float2bfloat16(x);
    return cv.s;
}

// ---- monomial index -> (deg,i,j,l), i<=j<=l (constexpr) --------------------
struct MIdx { int deg, i, j, l; };
__host__ __device__ constexpr MIdx decode_c(int idx) {
    if (idx < 9) return {1, idx, 0, 0};
    int t = idx - 9;
    for (int i = 0; i < 9; ++i)
        for (int j = i; j < 9; ++j) {
            int cnt = 10 - j;
            if (t < cnt) {
                if (t == 0) return {2, i, j, 0};
                return {3, i, j, j + t - 1};
            }
            t -= cnt;
        }
    return {0, 0, 0, 0};
}

// full per-k table (deg 0 marks k >= NM padding)
struct KTbl { MIdx v[224]; };
__host__ __device__ constexpr KTbl gen_ktbl() {
    KTbl t{};
    for (int k = 0; k < 224; ++k)
        t.v[k] = (k < NM) ? decode_c(k) : MIdx{0, 0, 0, 0};
    return t;
}
__device__ constexpr KTbl KT = gen_ktbl();

template<int K>
__device__ __forceinline__ float mono_val_t(const float a[9]) {
    if constexpr (K >= NM) return 0.f;
    else {
        constexpr MIdx d = decode_c(K);
        if constexpr (d.deg == 1) return a[d.i];
        else if constexpr (d.deg == 2) return a[d.i] * a[d.j];
        else return a[d.i] * a[d.j] * a[d.l];
    }
}

// pack two monomials to 2xbf16 in one dword (validated r4-r11)
template<int KB, int E2>
__device__ __forceinline__ unsigned pack2(const float a[9]) {
    const float lo = mono_val_t<KB + 2 * E2>(a);
    const float hi = mono_val_t<KB + 2 * E2 + 1>(a);
    return __builtin_amdgcn_perm(__float_as_uint(hi) + 0x8000u,
                                 __float_as_uint(lo) + 0x8000u, 0x07060302u);
}
template<int KB>
__device__ __forceinline__ uint4v build_granule(const float a[9]) {
    return uint4v{pack2<KB,0>(a), pack2<KB,1>(a), pack2<KB,2>(a), pack2<KB,3>(a)};
}

// ---- fused prep: symmetrize (block-local) + weight -> Wf fragments ---------
// grid (NSTEP, 16): block owns MFMA step s and channels [y*8, y*8+8)
__global__ __launch_bounds__(256) void symcon_prep(
    const float* __restrict__ Us1, const float* __restrict__ ws1,
    const float* __restrict__ Us2, const float* __restrict__ ws2,
    const float* __restrict__ Us3, const float* __restrict__ ws3,
    const float* __restrict__ Up1, const float* __restrict__ wp1,
    const float* __restrict__ Up2, const float* __restrict__ wp2,
    const float* __restrict__ Up3, const float* __restrict__ wp3,
    const float* __restrict__ Ud1, const float* __restrict__ wd1,
    const float* __restrict__ Ud2, const float* __restrict__ wd2,
    const float* __restrict__ Ud3, const float* __restrict__ wd3,
    short* __restrict__ Wf)
{
    const int s  = blockIdx.x;           // 0..6
    const int c0 = blockIdx.y * CL;      // 8 channels
    const int t  = threadIdx.x;

    // padded rows (20 floats = 80B) break the 128B-periodic bank pattern
    __shared__ float Us[32 * 180];       // [km][m][kk<=16 of 20] : 23040 B
    __shared__ float wld[9 * CL * 20];   // [type*3+deg-1][cl][kk] : 5760 B

    const float* Uall[3][3] = {{Us1, Us2, Us3}, {Up1, Up2, Up3}, {Ud1, Ud2, Ud3}};
    const float* Wall[3][3] = {{ws1, ws2, ws3}, {wp1, wp2, wp3}, {wd1, wd2, wd3}};
    const int    Kall[3][3] = {{1, 2, 5}, {1, 3, 8}, {1, 4, 10}};

    // ---- phase W: stage weight rows for this block's channels -------------
    for (int e = t; e < 9 * CL * 16; e += 256) {
        const int td = e / (CL * 16), r = e % (CL * 16);
        const int cl = r >> 4, kk = r & 15;
        const int type = td / 3, dg = td % 3;            // dg = deg-1
        const int K = Kall[type][dg];
        const float v = (kk < K) ? Wall[type][dg][kk * CFEAT + (c0 + cl)] : 0.f;
        wld[td * (CL * 20) + cl * 20 + kk] = v;
    }

    // ---- phase A: symmetrized U slice for this step's 32 monomials --------
    for (int e = t; e < 32 * 9 * 16; e += 256) {
        const int km = e / 144, r = e % 144;
        const int m = r >> 4, kk = r & 15;
        const int k = s * 32 + km;
        const MIdx d = KT.v[k];
        const int type = (m == 0) ? 0 : (m < 4 ? 1 : 2);
        const int ml = m - (type == 0 ? 0 : (type == 1 ? 1 : 4));
        float v = 0.f;
        if (d.deg != 0 && kk < Kall[type][d.deg - 1]) {
            const int i = d.i, j = d.j, l = d.l;
            if (d.deg == 1) {
                v = Uall[type][0][ml * 9 + i];
            } else if (d.deg == 2) {
                const int K2 = Kall[type][1];
                v = Uall[type][1][((size_t)(ml * 9 + i) * 9 + j) * K2 + kk];
                if (i != j) v += Uall[type][1][((size_t)(ml * 9 + j) * 9 + i) * K2 + kk];
            } else {
                const int K3 = Kall[type][2];
                const int e0=(i*9+j)*9+l, e1=(i*9+l)*9+j, e2=(j*9+i)*9+l,
                          e3=(j*9+l)*9+i, e4=(l*9+i)*9+j, e5=(l*9+j)*9+i;
                const float* B3 = Uall[type][2] + (size_t)ml * 729 * K3 + kk;
                v = B3[(size_t)e0 * K3];
                if (e1 != e0)                                     v += B3[(size_t)e1 * K3];
                if (e2 != e0 && e2 != e1)                         v += B3[(size_t)e2 * K3];
                if (e3 != e0 && e3 != e1 && e3 != e2)             v += B3[(size_t)e3 * K3];
                if (e4 != e0 && e4 != e1 && e4 != e2 && e4 != e3) v += B3[(size_t)e4 * K3];
                if (e5 != e0 && e5 != e1 && e5 != e2 && e5 != e3 && e5 != e4)
                                                                  v += B3[(size_t)e5 * K3];
            }
        }
        Us[km * 180 + m * 20 + kk] = v;
    }
    __syncthreads();

    // ---- phase B: W[k][m] = sum_kk Us * w, all 8 channels ------------------
    // thread owns slots t and t+256 (same m, km and km+16)
    const int lane0 = t >> 3, e8 = t & 7;
    const int m = lane0 & 15;
    #pragma unroll
    for (int half = 0; half < 2; ++half) {
        const int slot = t + half * 256;
        const int km = ((slot >> 7) << 3) | e8;          // ((lane>>4)<<3)+e
        const int k = s * 32 + km;
        const MIdx d = KT.v[k];
        if (m < 9 && d.deg != 0) {
            const int type = (m == 0) ? 0 : (m < 4 ? 1 : 2);
            const int td = type * 3 + (d.deg - 1);
            const float* up = &Us[km * 180 + m * 20];
            const f32x4 u0 = *(const f32x4*)(up);
            const f32x4 u1 = *(const f32x4*)(up + 4);
            const f32x4 u2 = *(const f32x4*)(up + 8);
            const f32x4 u3 = *(const f32x4*)(up + 12);
            #pragma unroll
            for (int cl = 0; cl < CL; ++cl) {
                const float* wp = &wld[td * (CL * 20) + cl * 20];
                const f32x4 w0 = *(const f32x4*)(wp);
                const f32x4 w1 = *(const f32x4*)(wp + 4);
                const f32x4 w2 = *(const f32x4*)(wp + 8);
                const f32x4 w3 = *(const f32x4*)(wp + 12);
                float v = 0.f;
                #pragma unroll
                for (int q = 0; q < 4; ++q) {
                    v = fmaf(u0[q], w0[q], v);
                    v = fmaf(u1[q], w1[q], v);
                    v = fmaf(u2[q], w2[q], v);
                    v = fmaf(u3[q], w3[q], v);
                }
                Wf[((size_t)(c0 + cl) * NSTEP + s) * 512 + slot] = f2bf(v);
            }
        } else {
            #pragma unroll
            for (int cl = 0; cl < CL; ++cl)
                Wf[((size_t)(c0 + cl) * NSTEP + s) * 512 + slot] = 0;
        }
    }
}

// ---- hot step (r6/r10 verbatim) --------------------------------------------
template<int S>
__device__ __forceinline__ void do_step(const float a[9], char* wrbase, const char* rdbase,
                                        const short8 bfrag[NSTEP], f32x4 acc[4])
{
    const uint4v g0 = build_granule<S * 32 +  0>(a);
    const uint4v g1 = build_granule<S * 32 +  8>(a);
    const uint4v g2 = build_granule<S * 32 + 16>(a);
    const uint4v g3 = build_granule<S * 32 + 24>(a);
    *(uint4v*)(wrbase       ) = g0;
    *(uint4v*)(wrbase + 1024) = g1;
    *(uint4v*)(wrbase + 2048) = g2;
    *(uint4v*)(wrbase + 3072) = g3;
    #pragma unroll
    for (int t = 0; t < 4; ++t) {
        short8 af = *(const short8*)(rdbase + t * 256);
        acc[t] = __builtin_amdgcn_mfma_f32_16x16x32_bf16(af, bfrag[S], acc[t], 0, 0, 0);
    }
}

// ---- hot: r10 verbatim (float4-vectorized staging) -------------------------
__global__ __launch_bounds__(256, 4) void symcon_hot(
    const float* __restrict__ A, const short* __restrict__ Wf, float* __restrict__ out)
{
    const int tid = threadIdx.x;
    const int w = tid >> 6, l = tid & 63;
    const int p = l & 15, q = l >> 4;
    const int c0 = blockIdx.x * 4;
    const int nb = blockIdx.y * 64;

    __shared__ float sA[64 * 37];                     // 9472 B staging (pad 37)
    __shared__ __align__(16) char phiAll[4 * 4096];   // 16 KB wave-private phi

    const size_t gbase = (size_t)nb * (CFEAT * 9) + (size_t)c0 * 9;

    #pragma unroll
    for (int e = tid; e < 576; e += 256) {
        const int n = e / 9, f = e - n * 9;
        const float4 v = *(const float4*)(A + gbase + (size_t)n * (CFEAT * 9) + f * 4);
        const int base = n * 37 + f * 4;
        sA[base] = v.x; sA[base + 1] = v.y; sA[base + 2] = v.z; sA[base + 3] = v.w;
    }

    const short8* Wc = (const short8*)Wf + (size_t)(c0 + w) * NSTEP * 64;
    short8 bfrag[NSTEP];
    #pragma unroll
    for (int s = 0; s < NSTEP; ++s) bfrag[s] = Wc[s * 64 + l];

    __syncthreads();

    float a[9];
    #pragma unroll
    for (int x = 0; x < 9; ++x) a[x] = sA[l * 37 + w * 9 + x];

    char* const phiW   = phiAll + w * 4096;
    char* const wrbase = phiW + l * 16;
    const char* const rdbase = phiW + q * 1024 + p * 16;

    f32x4 acc[4];
    #pragma unroll
    for (int t = 0; t < 4; ++t) acc[t] = f32x4{0.f, 0.f, 0.f, 0.f};

    do_step<0>(a, wrbase, rdbase, bfrag, acc);
    do_step<1>(a, wrbase, rdbase, bfrag, acc);
    do_step<2>(a, wrbase, rdbase, bfrag, acc);
    do_step<3>(a, wrbase, rdbase, bfrag, acc);
    do_step<4>(a, wrbase, rdbase, bfrag, acc);
    do_step<5>(a, wrbase, rdbase, bfrag, acc);
    do_step<6>(a, wrbase, rdbase, bfrag, acc);

    __syncthreads();
    if (p < 9) {
        #pragma unroll
        for (int t = 0; t < 4; ++t)
            #pragma unroll
            for (int r = 0; r < 4; ++r)
                sA[(t * 16 + q * 4 + r) * 37 + w * 9 + p] = acc[t][r];
    }
    __syncthreads();

    #pragma unroll
    for (int e = tid; e < 576; e += 256) {
        const int n = e / 9, f = e - n * 9;
        const int base = n * 37 + f * 4;
        const float4 v{sA[base], sA[base + 1], sA[base + 2], sA[base + 3]};
        *(float4*)(out + gbase + (size_t)n * (CFEAT * 9) + f * 4) = v;
    }
}

extern "C" void kernel_launch(void* const* d_in, const int* in_sizes, int n_in,
                              void* d_out, int out_size, void* d_ws, size_t ws_size,
                              hipStream_t stream)
{
    const float* A   = (const float*)d_in[0];
    const float* Us1 = (const float*)d_in[1];  const float* ws1 = (const float*)d_in[2];
    const float* Us2 = (const float*)d_in[3];  const float* ws2 = (const float*)d_in[4];
    const float* Us3 = (const float*)d_in[5];  const float* ws3 = (const float*)d_in[6];
    const float* Up1 = (const float*)d_in[7];  const float* wp1 = (const float*)d_in[8];
    const float* Up2 = (const float*)d_in[9];  const float* wp2 = (const float*)d_in[10];
    const float* Up3 = (const float*)d_in[11]; const float* wp3 = (const float*)d_in[12];
    const float* Ud1 = (const float*)d_in[13]; const float* wd1 = (const float*)d_in[14];
    const float* Ud2 = (const float*)d_in[15]; const float* wd2 = (const float*)d_in[16];
    const float* Ud3 = (const float*)d_in[17]; const float* wd3 = (const float*)d_in[18];
    float* out = (float*)d_out;
    short* Wf  = (short*)d_ws;

    symcon_prep<<<dim3(NSTEP, CFEAT / CL), 256, 0, stream>>>(
        Us1, ws1, Us2, ws2, Us3, ws3, Up1, wp1, Up2, wp2, Up3, wp3,
        Ud1, wd1, Ud2, wd2, Ud3, wd3, Wf);

    symcon_hot<<<dim3(CFEAT / 4, NODES / 64), 256, 0, stream>>>(A, Wf, out);
}

// Round 13
// 43.341 us; speedup vs baseline: 4.6199x; 1.1292x over previous
//
#include <hip/hip_runtime.h>
#include <hip/hip_bf16.h>

#define CFEAT 128
#define NODES 2048
#define NM    219            // 9 deg1 + 45 deg2 + 165 deg3 monomials
#define NSTEP 7              // K padded to 224 = 7*32 (16x16x32 MFMA)
#define CL    8              // channels per prep block

typedef __attribute__((ext_vector_type(8))) short short8;
typedef __attribute__((ext_vector_type(4))) float f32x4;
typedef __attribute__((ext_vector_type(4))) unsigned int uint4v;

__device__ __forceinline__ short f2bf(float x) {
    union { __hip_bfloat16 b; short s; } cv;
    cv.b = __float2bfloat16(x);
    return cv.s;
}

// ---- monomial index -> (deg,i,j,l), i<=j<=l (constexpr) --------------------
struct MIdx { int deg, i, j, l; };
__host__ __device__ constexpr MIdx decode_c(int idx) {
    if (idx < 9) return {1, idx, 0, 0};
    int t = idx - 9;
    for (int i = 0; i < 9; ++i)
        for (int j = i; j < 9; ++j) {
            int cnt = 10 - j;
            if (t < cnt) {
                if (t == 0) return {2, i, j, 0};
                return {3, i, j, j + t - 1};
            }
            t -= cnt;
        }
    return {0, 0, 0, 0};
}

// full per-k table (deg 0 marks k >= NM padding)
struct KTbl { MIdx v[224]; };
__host__ __device__ constexpr KTbl gen_ktbl() {
    KTbl t{};
    for (int k = 0; k < 224; ++k)
        t.v[k] = (k < NM) ? decode_c(k) : MIdx{0, 0, 0, 0};
    return t;
}
__device__ constexpr KTbl KT = gen_ktbl();

template<int K>
__device__ __forceinline__ float mono_val_t(const float a[9]) {
    if constexpr (K >= NM) return 0.f;
    else {
        constexpr MIdx d = decode_c(K);
        if constexpr (d.deg == 1) return a[d.i];
        else if constexpr (d.deg == 2) return a[d.i] * a[d.j];
        else return a[d.i] * a[d.j] * a[d.l];
    }
}

// pack two monomials to 2xbf16 in one dword (validated r4-r12)
template<int KB, int E2>
__device__ __forceinline__ unsigned pack2(const float a[9]) {
    const float lo = mono_val_t<KB + 2 * E2>(a);
    const float hi = mono_val_t<KB + 2 * E2 + 1>(a);
    return __builtin_amdgcn_perm(__float_as_uint(hi) + 0x8000u,
                                 __float_as_uint(lo) + 0x8000u, 0x07060302u);
}
template<int KB>
__device__ __forceinline__ uint4v build_granule(const float a[9]) {
    return uint4v{pack2<KB,0>(a), pack2<KB,1>(a), pack2<KB,2>(a), pack2<KB,3>(a)};
}

// ---- fused prep: symmetrize (block-local) + weight -> Wf fragments ---------
// grid (NSTEP, 16): block owns MFMA step s and channels [y*8, y*8+8)
// NO runtime-indexed arrays (rule #20) — all selection via cndmask ternaries.
__global__ __launch_bounds__(256) void symcon_prep(
    const float* __restrict__ Us1, const float* __restrict__ ws1,
    const float* __restrict__ Us2, const float* __restrict__ ws2,
    const float* __restrict__ Us3, const float* __restrict__ ws3,
    const float* __restrict__ Up1, const float* __restrict__ wp1,
    const float* __restrict__ Up2, const float* __restrict__ wp2,
    const float* __restrict__ Up3, const float* __restrict__ wp3,
    const float* __restrict__ Ud1, const float* __restrict__ wd1,
    const float* __restrict__ Ud2, const float* __restrict__ wd2,
    const float* __restrict__ Ud3, const float* __restrict__ wd3,
    short* __restrict__ Wf)
{
    const int s  = blockIdx.x;           // 0..6
    const int c0 = blockIdx.y * CL;      // 8 channels
    const int t  = threadIdx.x;

    // padded rows (20 floats = 80B) break the 128B-periodic bank pattern
    __shared__ float Us[32 * 180];       // [km][m][kk<=16 of 20] : 23040 B
    __shared__ float wld[9 * CL * 20];   // [type*3+deg-1][cl][kk] : 5760 B

    // ---- phase W: stage weight rows for this block's channels -------------
    for (int e = t; e < 9 * CL * 16; e += 256) {
        const int td = e / (CL * 16), r = e % (CL * 16);
        const int cl = r >> 4, kk = r & 15;
        const int type = td / 3, dg = td % 3;            // dg = deg-1
        const int K = (dg == 0) ? 1
                    : (dg == 1) ? (type == 0 ? 2 : (type == 1 ? 3 : 4))
                                : (type == 0 ? 5 : (type == 1 ? 8 : 10));
        const float* wp =
            (type == 0) ? ((dg == 0) ? ws1 : (dg == 1) ? ws2 : ws3)
          : (type == 1) ? ((dg == 0) ? wp1 : (dg == 1) ? wp2 : wp3)
                        : ((dg == 0) ? wd1 : (dg == 1) ? wd2 : wd3);
        const float v = (kk < K) ? wp[kk * CFEAT + (c0 + cl)] : 0.f;
        wld[td * (CL * 20) + cl * 20 + kk] = v;
    }

    // ---- phase A: symmetrized U slice for this step's 32 monomials --------
    for (int e = t; e < 32 * 9 * 16; e += 256) {
        const int km = e / 144, r = e % 144;
        const int m = r >> 4, kk = r & 15;
        const int k = s * 32 + km;
        const MIdx d = KT.v[k];
        const int type = (m == 0) ? 0 : (m < 4 ? 1 : 2);
        const int ml = (type == 0) ? 0 : (type == 1 ? m - 1 : m - 4);
        float v = 0.f;
        if (d.deg == 1) {
            const float* U1 = (type == 0) ? Us1 : (type == 1) ? Up1 : Ud1;
            if (kk < 1) v = U1[ml * 9 + d.i];
        } else if (d.deg == 2) {
            const int K2 = (type == 0) ? 2 : (type == 1 ? 3 : 4);
            const float* U2 = (type == 0) ? Us2 : (type == 1) ? Up2 : Ud2;
            if (kk < K2) {
                const int i = d.i, j = d.j;
                v = U2[((size_t)(ml * 9 + i) * 9 + j) * K2 + kk];
                if (i != j) v += U2[((size_t)(ml * 9 + j) * 9 + i) * K2 + kk];
            }
        } else if (d.deg == 3) {
            const int K3 = (type == 0) ? 5 : (type == 1 ? 8 : 10);
            const float* U3 = (type == 0) ? Us3 : (type == 1) ? Up3 : Ud3;
            if (kk < K3) {
                const int i = d.i, j = d.j, l = d.l;
                const int e0=(i*9+j)*9+l, e1=(i*9+l)*9+j, e2=(j*9+i)*9+l,
                          e3=(j*9+l)*9+i, e4=(l*9+i)*9+j, e5=(l*9+j)*9+i;
                const float* B3 = U3 + (size_t)ml * 729 * K3 + kk;
                v = B3[(size_t)e0 * K3];
                if (e1 != e0)                                     v += B3[(size_t)e1 * K3];
                if (e2 != e0 && e2 != e1)                         v += B3[(size_t)e2 * K3];
                if (e3 != e0 && e3 != e1 && e3 != e2)             v += B3[(size_t)e3 * K3];
                if (e4 != e0 && e4 != e1 && e4 != e2 && e4 != e3) v += B3[(size_t)e4 * K3];
                if (e5 != e0 && e5 != e1 && e5 != e2 && e5 != e3 && e5 != e4)
                                                                  v += B3[(size_t)e5 * K3];
            }
        }
        Us[km * 180 + m * 20 + kk] = v;
    }
    __syncthreads();

    // ---- phase B: W[k][m] = sum_kk Us * w, all 8 channels ------------------
    // thread owns slots t and t+256 (same m, km and km+16)
    const int lane0 = t >> 3, e8 = t & 7;
    const int m = lane0 & 15;
    #pragma unroll
    for (int half = 0; half < 2; ++half) {
        const int slot = t + half * 256;
        const int km = ((slot >> 7) << 3) | e8;          // ((lane>>4)<<3)+e
        const int k = s * 32 + km;
        const MIdx d = KT.v[k];
        if (m < 9 && d.deg != 0) {
            const int type = (m == 0) ? 0 : (m < 4 ? 1 : 2);
            const int td = type * 3 + (d.deg - 1);       // LDS index only — fine
            const float* up = &Us[km * 180 + m * 20];
            const f32x4 u0 = *(const f32x4*)(up);
            const f32x4 u1 = *(const f32x4*)(up + 4);
            const f32x4 u2 = *(const f32x4*)(up + 8);
            const f32x4 u3 = *(const f32x4*)(up + 12);
            #pragma unroll
            for (int cl = 0; cl < CL; ++cl) {
                const float* wp = &wld[td * (CL * 20) + cl * 20];
                const f32x4 w0 = *(const f32x4*)(wp);
                const f32x4 w1 = *(const f32x4*)(wp + 4);
                const f32x4 w2 = *(const f32x4*)(wp + 8);
                const f32x4 w3 = *(const f32x4*)(wp + 12);
                float v = 0.f;
                #pragma unroll
                for (int q = 0; q < 4; ++q) {
                    v = fmaf(u0[q], w0[q], v);
                    v = fmaf(u1[q], w1[q], v);
                    v = fmaf(u2[q], w2[q], v);
                    v = fmaf(u3[q], w3[q], v);
                }
                Wf[((size_t)(c0 + cl) * NSTEP + s) * 512 + slot] = f2bf(v);
            }
        } else {
            #pragma unroll
            for (int cl = 0; cl < CL; ++cl)
                Wf[((size_t)(c0 + cl) * NSTEP + s) * 512 + slot] = 0;
        }
    }
}

// ---- hot step (r6/r10 verbatim) --------------------------------------------
template<int S>
__device__ __forceinline__ void do_step(const float a[9], char* wrbase, const char* rdbase,
                                        const short8 bfrag[NSTEP], f32x4 acc[4])
{
    const uint4v g0 = build_granule<S * 32 +  0>(a);
    const uint4v g1 = build_granule<S * 32 +  8>(a);
    const uint4v g2 = build_granule<S * 32 + 16>(a);
    const uint4v g3 = build_granule<S * 32 + 24>(a);
    *(uint4v*)(wrbase       ) = g0;
    *(uint4v*)(wrbase + 1024) = g1;
    *(uint4v*)(wrbase + 2048) = g2;
    *(uint4v*)(wrbase + 3072) = g3;
    #pragma unroll
    for (int t = 0; t < 4; ++t) {
        short8 af = *(const short8*)(rdbase + t * 256);
        acc[t] = __builtin_amdgcn_mfma_f32_16x16x32_bf16(af, bfrag[S], acc[t], 0, 0, 0);
    }
}

// ---- hot: r10 verbatim (float4-vectorized staging) -------------------------
__global__ __launch_bounds__(256, 4) void symcon_hot(
    const float* __restrict__ A, const short* __restrict__ Wf, float* __restrict__ out)
{
    const int tid = threadIdx.x;
    const int w = tid >> 6, l = tid & 63;
    const int p = l & 15, q = l >> 4;
    const int c0 = blockIdx.x * 4;
    const int nb = blockIdx.y * 64;

    __shared__ float sA[64 * 37];                     // 9472 B staging (pad 37)
    __shared__ __align__(16) char phiAll[4 * 4096];   // 16 KB wave-private phi

    const size_t gbase = (size_t)nb * (CFEAT * 9) + (size_t)c0 * 9;

    #pragma unroll
    for (int e = tid; e < 576; e += 256) {
        const int n = e / 9, f = e - n * 9;
        const float4 v = *(const float4*)(A + gbase + (size_t)n * (CFEAT * 9) + f * 4);
        const int base = n * 37 + f * 4;
        sA[base] = v.x; sA[base + 1] = v.y; sA[base + 2] = v.z; sA[base + 3] = v.w;
    }

    const short8* Wc = (const short8*)Wf + (size_t)(c0 + w) * NSTEP * 64;
    short8 bfrag[NSTEP];
    #pragma unroll
    for (int s = 0; s < NSTEP; ++s) bfrag[s] = Wc[s * 64 + l];

    __syncthreads();

    float a[9];
    #pragma unroll
    for (int x = 0; x < 9; ++x) a[x] = sA[l * 37 + w * 9 + x];

    char* const phiW   = phiAll + w * 4096;
    char* const wrbase = phiW + l * 16;
    const char* const rdbase = phiW + q * 1024 + p * 16;

    f32x4 acc[4];
    #pragma unroll
    for (int t = 0; t < 4; ++t) acc[t] = f32x4{0.f, 0.f, 0.f, 0.f};

    do_step<0>(a, wrbase, rdbase, bfrag, acc);
    do_step<1>(a, wrbase, rdbase, bfrag, acc);
    do_step<2>(a, wrbase, rdbase, bfrag, acc);
    do_step<3>(a, wrbase, rdbase, bfrag, acc);
    do_step<4>(a, wrbase, rdbase, bfrag, acc);
    do_step<5>(a, wrbase, rdbase, bfrag, acc);
    do_step<6>(a, wrbase, rdbase, bfrag, acc);

    __syncthreads();
    if (p < 9) {
        #pragma unroll
        for (int t = 0; t < 4; ++t)
            #pragma unroll
            for (int r = 0; r < 4; ++r)
                sA[(t * 16 + q * 4 + r) * 37 + w * 9 + p] = acc[t][r];
    }
    __syncthreads();

    #pragma unroll
    for (int e = tid; e < 576; e += 256) {
        const int n = e / 9, f = e - n * 9;
        const int base = n * 37 + f * 4;
        const float4 v{sA[base], sA[base + 1], sA[base + 2], sA[base + 3]};
        *(float4*)(out + gbase + (size_t)n * (CFEAT * 9) + f * 4) = v;
    }
}

extern "C" void kernel_launch(void* const* d_in, const int* in_sizes, int n_in,
                              void* d_out, int out_size, void* d_ws, size_t ws_size,
                              hipStream_t stream)
{
    const float* A   = (const float*)d_in[0];
    const float* Us1 = (const float*)d_in[1];  const float* ws1 = (const float*)d_in[2];
    const float* Us2 = (const float*)d_in[3];  const float* ws2 = (const float*)d_in[4];
    const float* Us3 = (const float*)d_in[5];  const float* ws3 = (const float*)d_in[6];
    const float* Up1 = (const float*)d_in[7];  const float* wp1 = (const float*)d_in[8];
    const float* Up2 = (const float*)d_in[9];  const float* wp2 = (const float*)d_in[10];
    const float* Up3 = (const float*)d_in[11]; const float* wp3 = (const float*)d_in[12];
    const float* Ud1 = (const float*)d_in[13]; const float* wd1 = (const float*)d_in[14];
    const float* Ud2 = (const float*)d_in[15]; const float* wd2 = (const float*)d_in[16];
    const float* Ud3 = (const float*)d_in[17]; const float* wd3 = (const float*)d_in[18];
    float* out = (float*)d_out;
    short* Wf  = (short*)d_ws;

    symcon_prep<<<dim3(NSTEP, CFEAT / CL), 256, 0, stream>>>(
        Us1, ws1, Us2, ws2, Us3, ws3, Up1, wp1, Up2, wp2, Up3, wp3,
        Ud1, wd1, Ud2, wd2, Ud3, wd3, Wf);

    symcon_hot<<<dim3(CFEAT / 4, NODES / 64), 256, 0, stream>>>(A, Wf, out);
}

// Round 14
// 28.060 us; speedup vs baseline: 7.1358x; 1.5446x over previous
//
#include <hip/hip_runtime.h>
#include <hip/hip_bf16.h>

#define CFEAT 128
#define NODES 2048
#define NM    219            // 9 deg1 + 45 deg2 + 165 deg3 monomials
#define NSTEP 7              // K padded to 224 = 7*32 (16x16x32 MFMA)

typedef __attribute__((ext_vector_type(8))) short short8;
typedef __attribute__((ext_vector_type(4))) float f32x4;
typedef __attribute__((ext_vector_type(4))) unsigned int uint4v;

// ---- ws float offsets: [0, 917504B) = Wf bf16 fragments, then: ------------
#define OFF3 262144                          // U3s [9][165][16]
#define OFF2 (OFF3 + 9*165*16)               // U2s [9][45][4]
#define OFF1 (OFF2 + 9*45*4)                 // U1s [9][9]

__device__ __forceinline__ short f2bf(float x) {
    union { __hip_bfloat16 b; short s; } cv;
    cv.b = __float2bfloat16(x);
    return cv.s;
}

// ---- monomial index -> (deg,i,j,l), i<=j<=l (constexpr) --------------------
struct MIdx { int deg, i, j, l; };
__host__ __device__ constexpr MIdx decode_c(int idx) {
    if (idx < 9) return {1, idx, 0, 0};
    int t = idx - 9;
    for (int i = 0; i < 9; ++i)
        for (int j = i; j < 9; ++j) {
            int cnt = 10 - j;
            if (t < cnt) {
                if (t == 0) return {2, i, j, 0};
                return {3, i, j, j + t - 1};
            }
            t -= cnt;
        }
    return {0, 0, 0, 0};
}
__host__ __device__ constexpr int h2c(int n) { return n * (n + 1) / 2; }
__host__ __device__ constexpr int g3c(int n) { return n * (n + 1) * (n + 2) / 6; }
__host__ __device__ constexpr int tri3c(int i, int j, int l) {
    return (165 - g3c(9 - i)) + (h2c(9 - i) - h2c(9 - j)) + (l - j);
}
__host__ __device__ constexpr int pair2c(int i, int j) {
    return (45 - h2c(9 - i)) + (j - i);
}

struct MTbl { int v[224]; };
__host__ __device__ constexpr MTbl gen_tbl() {
    MTbl t{};
    for (int k = 0; k < 224; ++k) {
        if (k < NM) {
            MIdx d = decode_c(k);
            int sub = (d.deg == 1) ? d.i : (d.deg == 2) ? pair2c(d.i, d.j)
                                                        : tri3c(d.i, d.j, d.l);
            t.v[k] = d.deg | (sub << 4);
        } else t.v[k] = 0;
    }
    return t;
}
__device__ constexpr MTbl MONO_TBL = gen_tbl();

template<int K>
__device__ __forceinline__ float mono_val_t(const float a[9]) {
    if constexpr (K >= NM) return 0.f;
    else {
        constexpr MIdx d = decode_c(K);
        if constexpr (d.deg == 1) return a[d.i];
        else if constexpr (d.deg == 2) return a[d.i] * a[d.j];
        else return a[d.i] * a[d.j] * a[d.l];
    }
}

// pack two monomials to 2xbf16 in one dword.
// Plain __float2bfloat16 pairs: compiler fuses to v_cvt_pk_bf16_f32 (RNE, 1 inst)
// [learn_hip m240: use casts, NOT inline-asm cvt_pk]. Replaces perm+2add pack.
template<int KB, int E2>
__device__ __forceinline__ unsigned pack2(const float a[9]) {
    union { struct { short lo, hi; } p; unsigned u; } cv;
    cv.p.lo = f2bf(mono_val_t<KB + 2 * E2>(a));
    cv.p.hi = f2bf(mono_val_t<KB + 2 * E2 + 1>(a));
    return cv.u;
}
template<int KB>
__device__ __forceinline__ uint4v build_granule(const float a[9]) {
    return uint4v{pack2<KB,0>(a), pack2<KB,1>(a), pack2<KB,2>(a), pack2<KB,3>(a)};
}

// ---- P1: channel-independent symmetrization (r6/r10 verbatim) --------------
__global__ __launch_bounds__(256) void symcon_p1(
    const float* __restrict__ Us1, const float* __restrict__ Us2, const float* __restrict__ Us3,
    const float* __restrict__ Up1, const float* __restrict__ Up2, const float* __restrict__ Up3,
    const float* __restrict__ Ud1, const float* __restrict__ Ud2, const float* __restrict__ Ud3,
    float* __restrict__ ws_f)
{
    const int mg = blockIdx.x;
    const int y  = blockIdx.y;
    const int t  = threadIdx.x;

    const float *U1, *U2, *U3; int K2, K3, ml;
    if (mg == 0)     { U1 = Us1; U2 = Us2; U3 = Us3; K2 = 2; K3 = 5;  ml = 0; }
    else if (mg < 4) { U1 = Up1; U2 = Up2; U3 = Up3; K2 = 3; K3 = 8;  ml = mg - 1; }
    else             { U1 = Ud1; U2 = Ud2; U3 = Ud3; K2 = 4; K3 = 10; ml = mg - 4; }

    if (y < 11) {
        if (t >= 240) return;
        const int tri = y * 15 + (t >> 4);
        const int k   = t & 15;
        if (k >= K3) return;
        int i = 0, j = 0, l = 0, r = tri;
        bool done = false;
        for (i = 0; i < 9 && !done; ++i)
            for (j = i; j < 9; ++j) {
                int cnt = 9 - j;
                if (r < cnt) { l = j + r; done = true; break; }
                r -= cnt;
            }
        --i;
        const int e0=(i*9+j)*9+l, e1=(i*9+l)*9+j, e2=(j*9+i)*9+l,
                  e3=(j*9+l)*9+i, e4=(l*9+i)*9+j, e5=(l*9+j)*9+i;
        const float* B3 = U3 + (size_t)ml * 729 * K3 + k;
        float v = B3[(size_t)e0 * K3];
        if (e1 != e0)                                     v += B3[(size_t)e1 * K3];
        if (e2 != e0 && e2 != e1)                         v += B3[(size_t)e2 * K3];
        if (e3 != e0 && e3 != e1 && e3 != e2)             v += B3[(size_t)e3 * K3];
        if (e4 != e0 && e4 != e1 && e4 != e2 && e4 != e3) v += B3[(size_t)e4 * K3];
        if (e5 != e0 && e5 != e1 && e5 != e2 && e5 != e3 && e5 != e4)
                                                          v += B3[(size_t)e5 * K3];
        ws_f[OFF3 + (mg * 165 + tri) * 16 + k] = v;
    } else {
        if (t < 180) {
            int pr = t >> 2, k = t & 3;
            if (k >= K2) return;
            int i = 0, j = 0, r = pr;
            for (i = 0; i < 9; ++i) {
                int cnt = 9 - i;
                if (r < cnt) { j = i + r; break; }
                r -= cnt;
            }
            float v = U2[((size_t)(ml * 9 + i) * 9 + j) * K2 + k];
            if (i != j) v += U2[((size_t)(ml * 9 + j) * 9 + i) * K2 + k];
            ws_f[OFF2 + (mg * 45 + pr) * 4 + k] = v;
        } else if (t < 189) {
            const int i = t - 180;
            ws_f[OFF1 + mg * 9 + i] = U1[ml * 9 + i];
        }
    }
}

// ---- P2: per-channel weighting into bf16 B-fragment layout (r10 verbatim) --
__global__ __launch_bounds__(256) void symcon_p2(
    const float* __restrict__ ws_f,
    const float* __restrict__ ws1, const float* __restrict__ ws2, const float* __restrict__ ws3,
    const float* __restrict__ wp1, const float* __restrict__ wp2, const float* __restrict__ wp3,
    const float* __restrict__ wd1, const float* __restrict__ wd2, const float* __restrict__ wd3,
    short* __restrict__ Wf)
{
    const int c = blockIdx.x, s = blockIdx.y >> 1;
    const int slot = ((blockIdx.y & 1) << 8) | threadIdx.x;
    const int lane = slot >> 3, e = slot & 7;
    const int k = s * 32 + ((lane >> 4) * 8) + e;
    const int m = lane & 15;
    float v = 0.f;
    if (k < NM && m < 9) {
        const int pk  = MONO_TBL.v[k];
        const int deg = pk & 15, sub = pk >> 4;
        const float *w1, *w2, *w3; int K2, K3;
        if (m == 0)     { w1 = ws1; w2 = ws2; w3 = ws3; K2 = 2; K3 = 5;  }
        else if (m < 4) { w1 = wp1; w2 = wp2; w3 = wp3; K2 = 3; K3 = 8;  }
        else            { w1 = wd1; w2 = wd2; w3 = wd3; K2 = 4; K3 = 10; }
        if (deg == 1) {
            v = ws_f[OFF1 + m * 9 + sub] * w1[c];
        } else if (deg == 2) {
            const float* u = ws_f + OFF2 + (m * 45 + sub) * 4;
            for (int kk = 0; kk < K2; ++kk) v = fmaf(u[kk], w2[kk * CFEAT + c], v);
        } else {
            const float* u = ws_f + OFF3 + (m * 165 + sub) * 16;
            for (int kk = 0; kk < K3; ++kk) v = fmaf(u[kk], w3[kk * CFEAT + c], v);
        }
    }
    Wf[(((size_t)c * NSTEP + s) * 64 + lane) * 8 + e] = f2bf(v);
}

// ---- hot step (r6 structure; pack now cvt_pk-based) ------------------------
template<int S>
__device__ __forceinline__ void do_step(const float a[9], char* wrbase, const char* rdbase,
                                        const short8 bfrag[NSTEP], f32x4 acc[4])
{
    const uint4v g0 = build_granule<S * 32 +  0>(a);
    const uint4v g1 = build_granule<S * 32 +  8>(a);
    const uint4v g2 = build_granule<S * 32 + 16>(a);
    const uint4v g3 = build_granule<S * 32 + 24>(a);
    *(uint4v*)(wrbase       ) = g0;
    *(uint4v*)(wrbase + 1024) = g1;
    *(uint4v*)(wrbase + 2048) = g2;
    *(uint4v*)(wrbase + 3072) = g3;
    #pragma unroll
    for (int t = 0; t < 4; ++t) {
        short8 af = *(const short8*)(rdbase + t * 256);
        acc[t] = __builtin_amdgcn_mfma_f32_16x16x32_bf16(af, bfrag[S], acc[t], 0, 0, 0);
    }
}

// ---- hot: r10 verbatim (float4-vectorized staging) -------------------------
__global__ __launch_bounds__(256, 4) void symcon_hot(
    const float* __restrict__ A, const short* __restrict__ Wf, float* __restrict__ out)
{
    const int tid = threadIdx.x;
    const int w = tid >> 6, l = tid & 63;
    const int p = l & 15, q = l >> 4;
    const int c0 = blockIdx.x * 4;
    const int nb = blockIdx.y * 64;

    __shared__ float sA[64 * 37];                     // 9472 B staging (pad 37)
    __shared__ __align__(16) char phiAll[4 * 4096];   // 16 KB wave-private phi

    const size_t gbase = (size_t)nb * (CFEAT * 9) + (size_t)c0 * 9;

    #pragma unroll
    for (int e = tid; e < 576; e += 256) {
        const int n = e / 9, f = e - n * 9;
        const float4 v = *(const float4*)(A + gbase + (size_t)n * (CFEAT * 9) + f * 4);
        const int base = n * 37 + f * 4;
        sA[base] = v.x; sA[base + 1] = v.y; sA[base + 2] = v.z; sA[base + 3] = v.w;
    }

    const short8* Wc = (const short8*)Wf + (size_t)(c0 + w) * NSTEP * 64;
    short8 bfrag[NSTEP];
    #pragma unroll
    for (int s = 0; s < NSTEP; ++s) bfrag[s] = Wc[s * 64 + l];

    __syncthreads();

    float a[9];
    #pragma unroll
    for (int x = 0; x < 9; ++x) a[x] = sA[l * 37 + w * 9 + x];

    char* const phiW   = phiAll + w * 4096;
    char* const wrbase = phiW + l * 16;
    const char* const rdbase = phiW + q * 1024 + p * 16;

    f32x4 acc[4];
    #pragma unroll
    for (int t = 0; t < 4; ++t) acc[t] = f32x4{0.f, 0.f, 0.f, 0.f};

    do_step<0>(a, wrbase, rdbase, bfrag, acc);
    do_step<1>(a, wrbase, rdbase, bfrag, acc);
    do_step<2>(a, wrbase, rdbase, bfrag, acc);
    do_step<3>(a, wrbase, rdbase, bfrag, acc);
    do_step<4>(a, wrbase, rdbase, bfrag, acc);
    do_step<5>(a, wrbase, rdbase, bfrag, acc);
    do_step<6>(a, wrbase, rdbase, bfrag, acc);

    __syncthreads();
    if (p < 9) {
        #pragma unroll
        for (int t = 0; t < 4; ++t)
            #pragma unroll
            for (int r = 0; r < 4; ++r)
                sA[(t * 16 + q * 4 + r) * 37 + w * 9 + p] = acc[t][r];
    }
    __syncthreads();

    #pragma unroll
    for (int e = tid; e < 576; e += 256) {
        const int n = e / 9, f = e - n * 9;
        const int base = n * 37 + f * 4;
        const float4 v{sA[base], sA[base + 1], sA[base + 2], sA[base + 3]};
        *(float4*)(out + gbase + (size_t)n * (CFEAT * 9) + f * 4) = v;
    }
}

extern "C" void kernel_launch(void* const* d_in, const int* in_sizes, int n_in,
                              void* d_out, int out_size, void* d_ws, size_t ws_size,
                              hipStream_t stream)
{
    const float* A   = (const float*)d_in[0];
    const float* Us1 = (const float*)d_in[1];  const float* ws1 = (const float*)d_in[2];
    const float* Us2 = (const float*)d_in[3];  const float* ws2 = (const float*)d_in[4];
    const float* Us3 = (const float*)d_in[5];  const float* ws3 = (const float*)d_in[6];
    const float* Up1 = (const float*)d_in[7];  const float* wp1 = (const float*)d_in[8];
    const float* Up2 = (const float*)d_in[9];  const float* wp2 = (const float*)d_in[10];
    const float* Up3 = (const float*)d_in[11]; const float* wp3 = (const float*)d_in[12];
    const float* Ud1 = (const float*)d_in[13]; const float* wd1 = (const float*)d_in[14];
    const float* Ud2 = (const float*)d_in[15]; const float* wd2 = (const float*)d_in[16];
    const float* Ud3 = (const float*)d_in[17]; const float* wd3 = (const float*)d_in[18];
    float* out  = (float*)d_out;
    float* ws_f = (float*)d_ws;
    short* Wf   = (short*)d_ws;

    symcon_p1<<<dim3(9, 12), 256, 0, stream>>>(
        Us1, Us2, Us3, Up1, Up2, Up3, Ud1, Ud2, Ud3, ws_f);

    symcon_p2<<<dim3(CFEAT, NSTEP * 2), 256, 0, stream>>>(
        ws_f, ws1, ws2, ws3, wp1, wp2, wp3, wd1, wd2, wd3, Wf);

    symcon_hot<<<dim3(CFEAT / 4, NODES / 64), 256, 0, stream>>>(A, Wf, out);
}